// Round 2
// baseline (548.785 us; speedup 1.0000x reference)
//
#include <hip/hip_runtime.h>
#include <hip/hip_bf16.h>

// Problem constants (match reference)
constexpr int N  = 50000;    // nodes
constexpr int E  = 1600000;  // edges
constexpr int CH = 128;      // in/out channels

// Workspace layout (bytes)
constexpr size_t H_OFF     = 0;                       // h = x@W^T + b   [N*CH] f32
constexpr size_t H_BYTES   = (size_t)N * CH * 4;      // 25,600,000
constexpr size_t CSR_OFF   = H_OFF + H_BYTES;         // csr src ids     [E] i32
constexpr size_t CSR_BYTES = (size_t)E * 4;           // 6,400,000
constexpr size_t DEG_BYTES = 200192;                  // 50048 ints, 256-divisible
constexpr size_t DEG_OFF   = CSR_OFF + CSR_BYTES;     // degree          [N] i32
constexpr size_t OFFS_OFF  = DEG_OFF + DEG_BYTES;     // csr offsets     [N] i32
constexpr size_t CUR_OFF   = OFFS_OFF + DEG_BYTES;    // scatter cursors [N] i32
constexpr size_t BS_OFF    = CUR_OFF + DEG_BYTES;     // block sums (49) i32
constexpr size_t REQUIRED  = BS_OFF + 256;            // ~32.6 MB

// ---------------- GEMM: h = x @ W^T + b ----------------
// 16 x-rows per block, 256 threads. W staged in LDS in two 64-row halves
// (total static LDS = (16+64)*129*4 = 41,280 B < 64 KB). Stride 129 breaks
// the power-of-2 bank pattern (2-way residual aliasing = free on CDNA4).
__global__ __launch_bounds__(256) void gemm_bias(const float* __restrict__ x,
                                                 const float* __restrict__ W,
                                                 const float* __restrict__ b,
                                                 float* __restrict__ h) {
    __shared__ float xs[16 * 129];
    __shared__ float ws[64 * 129];
    const int t  = threadIdx.x;
    const int r0 = blockIdx.x * 16;

    // Stage x tile: 16*128 floats = 512 float4, 2 per thread
    {
        const float4* x4 = (const float4*)(x + (size_t)r0 * CH);
        for (int i = 0; i < 2; i++) {
            int idx = t + i * 256;          // float4 index within tile
            float4 v = x4[idx];
            int r = idx >> 5;               // 32 float4 per row
            int d = (idx & 31) * 4;
            float* p = &xs[r * 129 + d];
            p[0] = v.x; p[1] = v.y; p[2] = v.z; p[3] = v.w;
        }
    }

    const int tc = (t & 15) * 4;   // 4 consecutive output cols (within 64-half)
    const int tr = t >> 4;         // row 0..15

    for (int half = 0; half < 2; half++) {
        __syncthreads();           // protect ws from previous iteration's readers
        // Stage W rows [half*64, half*64+64): 64*128 floats = 2048 float4, 8/thread
        const float4* W4 = (const float4*)(W + (size_t)half * 64 * CH);
        for (int i = 0; i < 8; i++) {
            int idx = t + i * 256;
            float4 v = W4[idx];
            int o = idx >> 5;
            int d = (idx & 31) * 4;
            float* p = &ws[o * 129 + d];
            p[0] = v.x; p[1] = v.y; p[2] = v.z; p[3] = v.w;
        }
        __syncthreads();

        float acc0 = 0.f, acc1 = 0.f, acc2 = 0.f, acc3 = 0.f;
#pragma unroll 4
        for (int k = 0; k < 128; k++) {
            float xv = xs[tr * 129 + k];
            acc0 += xv * ws[(tc + 0) * 129 + k];
            acc1 += xv * ws[(tc + 1) * 129 + k];
            acc2 += xv * ws[(tc + 2) * 129 + k];
            acc3 += xv * ws[(tc + 3) * 129 + k];
        }
        int col = half * 64 + tc;
        float4 r;
        r.x = acc0 + b[col + 0];
        r.y = acc1 + b[col + 1];
        r.z = acc2 + b[col + 2];
        r.w = acc3 + b[col + 3];
        // 50000 % 16 == 0: no row guard needed
        *(float4*)(h + (size_t)(r0 + tr) * CH + col) = r;
    }
}

// ---------------- degree histogram ----------------
__global__ void hist_kernel(const int* __restrict__ ei, int* __restrict__ deg) {
    int e = blockIdx.x * blockDim.x + threadIdx.x;
    if (e < E) {
        int d = ei[e];   // row 0 = dst
        atomicAdd(&deg[d], 1);
    }
}

// ---------------- exclusive scan, phase 1 (per-block) ----------------
__global__ __launch_bounds__(1024) void scan1(const int* __restrict__ deg,
                                              int* __restrict__ offs,
                                              int* __restrict__ bsums) {
    __shared__ int s[1024];
    int t = threadIdx.x;
    int gi = blockIdx.x * 1024 + t;
    int v = (gi < N) ? deg[gi] : 0;
    s[t] = v;
    __syncthreads();
    for (int o = 1; o < 1024; o <<= 1) {
        int tmp = (t >= o) ? s[t - o] : 0;
        __syncthreads();
        s[t] += tmp;
        __syncthreads();
    }
    if (gi < N) offs[gi] = s[t] - v;     // exclusive within block
    if (t == 1023) bsums[blockIdx.x] = s[t];
}

// ---------------- scan phase 2 (49 block totals, serial) ----------------
__global__ void scan2(int* __restrict__ bsums, int nb) {
    if (threadIdx.x == 0 && blockIdx.x == 0) {
        int run = 0;
        for (int i = 0; i < nb; i++) { int v = bsums[i]; bsums[i] = run; run += v; }
    }
}

// ---------------- scan phase 3 (add block offset, init cursors) ----------------
__global__ void scan3(int* __restrict__ offs, const int* __restrict__ bsums,
                      int* __restrict__ cur) {
    int gi = blockIdx.x * blockDim.x + threadIdx.x;
    if (gi < N) {
        int o = offs[gi] + bsums[gi >> 10];
        offs[gi] = o;
        cur[gi] = o;
    }
}

// ---------------- scatter edges into CSR ----------------
__global__ void scatter_kernel(const int* __restrict__ ei,
                               int* __restrict__ cur, int* __restrict__ csr) {
    int e = blockIdx.x * blockDim.x + threadIdx.x;
    if (e < E) {
        int d = ei[e];        // dst
        int s = ei[E + e];    // src
        int pos = atomicAdd(&cur[d], 1);
        csr[pos] = s;
    }
}

// ---------------- pull-mode aggregation ----------------
__global__ __launch_bounds__(128) void agg_kernel(const float* __restrict__ h,
                                                  const int* __restrict__ offs,
                                                  const int* __restrict__ deg,
                                                  const int* __restrict__ csr,
                                                  float* __restrict__ out) {
    int n = blockIdx.x;
    int c = threadIdx.x;
    int st = offs[n];
    int cnt = deg[n];
    float acc = 0.f;
    for (int i = 0; i < cnt; i++) {
        int s = csr[st + i];
        acc += h[(size_t)s * CH + c];
    }
    out[(size_t)n * CH + c] = acc;   // every n written; deg==0 -> 0
}

// ---------------- fallback: direct atomic scatter (needs only h in ws) ----------------
__global__ void atomic_agg(const float* __restrict__ h, const int* __restrict__ ei,
                           float* __restrict__ out) {
    int tid = blockIdx.x * blockDim.x + threadIdx.x;
    int e  = tid >> 5;          // 32 threads per edge, float4 each
    int cg = (tid & 31) * 4;
    if (e < E) {
        int d = ei[e];
        int s = ei[E + e];
        float4 v = *(const float4*)(h + (size_t)s * CH + cg);
        float* o = out + (size_t)d * CH + cg;
        atomicAdd(o + 0, v.x);
        atomicAdd(o + 1, v.y);
        atomicAdd(o + 2, v.z);
        atomicAdd(o + 3, v.w);
    }
}

extern "C" void kernel_launch(void* const* d_in, const int* in_sizes, int n_in,
                              void* d_out, int out_size, void* d_ws, size_t ws_size,
                              hipStream_t stream) {
    const float* x  = (const float*)d_in[0];
    const int*   ei = (const int*)d_in[1];   // int32 per harness contract
    const float* W  = (const float*)d_in[2];
    const float* b  = (const float*)d_in[3];
    float* out = (float*)d_out;

    char* ws = (char*)d_ws;
    float* h = (float*)(ws + H_OFF);

    // GEMM first (h is needed by both paths)
    gemm_bias<<<N / 16, 256, 0, stream>>>(x, W, b, h);

    if (ws_size >= REQUIRED) {
        int* csr   = (int*)(ws + CSR_OFF);
        int* deg   = (int*)(ws + DEG_OFF);
        int* offs  = (int*)(ws + OFFS_OFF);
        int* cur   = (int*)(ws + CUR_OFF);
        int* bsums = (int*)(ws + BS_OFF);

        hipMemsetAsync(deg, 0, DEG_BYTES, stream);  // ws re-poisoned every call
        hist_kernel<<<(E + 255) / 256, 256, 0, stream>>>(ei, deg);
        scan1<<<(N + 1023) / 1024, 1024, 0, stream>>>(deg, offs, bsums);
        scan2<<<1, 64, 0, stream>>>(bsums, (N + 1023) / 1024);
        scan3<<<(N + 255) / 256, 256, 0, stream>>>(offs, bsums, cur);
        scatter_kernel<<<(E + 255) / 256, 256, 0, stream>>>(ei, cur, csr);
        agg_kernel<<<N, 128, 0, stream>>>(h, offs, deg, csr, out);
    } else {
        // Fallback: atomic scatter straight into out (out must be zeroed — the
        // harness poisons it with 0xAA before every timed launch)
        hipMemsetAsync(out, 0, (size_t)out_size * sizeof(float), stream);
        int total = E * 32;
        atomic_agg<<<(total + 255) / 256, 256, 0, stream>>>(h, ei, out);
    }
}